// Round 3
// baseline (4596.887 us; speedup 1.0000x reference)
//
#include <hip/hip_runtime.h>

// ---------------------------------------------------------------------------
// VanillaCRF forward on MI355X — persistent-chain version, scoped-coherence
// edition.
//
// Identical compute/dataflow to the verified round-2 kernel (absmax 0.0).
// Changed: cross-XCD visibility of the recurrent h state.
//   OLD: bulk  buffer_wbl2 sc1  +  buffer_inv sc0 sc1  per block per step.
//        The inv wipes the whole per-XCD L2, so W1x streaming, xw reads and
//        hx=B0[t] re-fetch cold every iteration (~300 KB/block/iter).
//   NEW: h READS of intra-kernel-written slots use system-scope relaxed
//        loads (global_load_dwordx2 sc0 sc1 -> bypass L1/L2, read IC).
//        Release keeps ONE buffer_wbl2 sc1 per block (flush dirty h lines).
//        NO buffer_inv: read-only data (W1x, xw, B0-from-phase1) stays
//        permanently warm in L2 across all 128 steps.
// ---------------------------------------------------------------------------

typedef short v8s __attribute__((ext_vector_type(8)));
typedef float v4f __attribute__((ext_vector_type(4)));
typedef unsigned short u16;
typedef unsigned long long u64;

#define MFMA(a, b, c) __builtin_amdgcn_mfma_f32_16x16x32_bf16((a), (b), (c), 0, 0, 0)

static constexpr size_t WMAT    = (size_t)96 * 3072 * 8;   // u16 elems per 3072x768 kp matrix
static constexpr size_t SLOT16  = (size_t)96 * 16 * 8;
static constexpr size_t SLOT64  = (size_t)96 * 64 * 8;
static constexpr size_t SLOT128 = (size_t)96 * 128 * 8;

static constexpr size_t OFF_EM   = 0;
static constexpr size_t SZ_EM    = (size_t)2 * 64 * 128 * 2 * 4;
static constexpr size_t OFF_XW0  = OFF_EM + SZ_EM;
static constexpr size_t SZ_XW    = (size_t)4 * 128 * 3072 * 4;
static constexpr size_t OFF_XW1  = OFF_XW0 + SZ_XW;
static constexpr size_t OFF_SEQ  = OFF_XW1 + SZ_XW;
static constexpr size_t SZ_SEQ   = SLOT128 * 2;
static constexpr size_t OFF_LABS = OFF_SEQ + SZ_SEQ;     // 512 B
static constexpr size_t OFF_BAR  = OFF_LABS + 512;       // 16 KB (8 chains x 512 u32)
static constexpr size_t SZ_BAR   = 16384;
static constexpr size_t OFF_W0   = OFF_BAR + SZ_BAR;
static constexpr size_t SZ_W4    = (size_t)4 * WMAT * 2;
static constexpr size_t OFF_W1X  = OFF_W0 + SZ_W4;
static constexpr size_t OFF_W1R  = OFF_W1X + SZ_W4;
static constexpr size_t OFF_F0   = OFF_W1R + SZ_W4;
static constexpr size_t SZ_F0    = (size_t)2 * 129 * SLOT16 * 2;
static constexpr size_t OFF_H0F  = OFF_F0 + SZ_F0;
static constexpr size_t SZ_H0F   = (size_t)2 * SLOT128 * 2;
static constexpr size_t OFF_B0   = OFF_H0F + SZ_H0F;
static constexpr size_t SZ_S64   = (size_t)2 * 129 * SLOT64 * 2;
static constexpr size_t OFF_F1   = OFF_B0 + SZ_S64;
static constexpr size_t OFF_B1   = OFF_F1 + SZ_S64;
static constexpr size_t WS_NEED  = OFF_B1 + SZ_S64;      // ~145 MB

static __device__ __forceinline__ u16 f2b(float f) {
  unsigned int u = __float_as_uint(f);
  unsigned int r = (u + 0x7FFFu + ((u >> 16) & 1u)) >> 16;   // RNE
  return (u16)r;
}
static __device__ __forceinline__ float b2f(u16 u) {
  return __uint_as_float(((unsigned int)u) << 16);
}
static __device__ __forceinline__ float sigf(float x) {
  return 1.0f / (1.0f + __expf(-x));
}
static __device__ __forceinline__ float tanhfast(float x) {
  return 1.0f - 2.0f / (__expf(2.0f * x) + 1.0f);
}
static __device__ __forceinline__ float lse2(float a, float b) {
  float mx = fmaxf(a, b);
  return mx + __logf(__expf(a - mx) + __expf(b - mx));
}

// async global->LDS, 16B per lane; LDS base wave-uniform, +lane*16 implicit
static __device__ __forceinline__ void gl2lds16(const void* g, void* l) {
  __builtin_amdgcn_global_load_lds((const __attribute__((address_space(1))) unsigned int*)g,
                                   (__attribute__((address_space(3))) unsigned int*)l,
                                   16, 0, 0);
}

// system-scope relaxed 16B load: two global_load_dwordx2 sc0 sc1 (bypass
// L1/L2, read the coherent IC). Compiler tracks vmcnt -> loads pipeline.
static __device__ __forceinline__ v8s ld16_sys(const v8s* p) {
  u64* q = (u64*)p;
  union { u64 q2[2]; v8s v; } uu;
  uu.q2[0] = __hip_atomic_load(q + 0, __ATOMIC_RELAXED, __HIP_MEMORY_SCOPE_SYSTEM);
  uu.q2[1] = __hip_atomic_load(q + 1, __ATOMIC_RELAXED, __HIP_MEMORY_SCOPE_SYSTEM);
  return uu.v;
}

// ---------------------------------------------------------------------------
// Monotonic 2-level tree barrier, release = one wbl2 per block (no inv).
// base: per-chain region of 512 u32 (2 KB).
//   sub-line g (g=0..7): base + g*32 ; top: base + 256 ; gen: base + 288
// Caller: data stores done + __syncthreads() (drains every wave's vmcnt).
static __device__ __forceinline__ void tree_bar(unsigned* base, int grp, unsigned target) {
  if (threadIdx.x == 0) {
    // release: flush this block's dirty h lines from L2 to the IC
    asm volatile("s_waitcnt vmcnt(0)" ::: "memory");
    asm volatile("buffer_wbl2 sc1" ::: "memory");
    asm volatile("s_waitcnt vmcnt(0)" ::: "memory");
    unsigned o1 = __hip_atomic_fetch_add(base + grp * 32, 1u,
                                         __ATOMIC_RELAXED, __HIP_MEMORY_SCOPE_AGENT);
    if ((o1 % 6u) == 5u) {   // 6th arrival on this sub-line this step
      unsigned o2 = __hip_atomic_fetch_add(base + 256, 1u,
                                           __ATOMIC_RELAXED, __HIP_MEMORY_SCOPE_AGENT);
      if ((o2 % 8u) == 7u) { // 8th sub-group leader this step
        __hip_atomic_fetch_add(base + 288, 1u,
                               __ATOMIC_RELAXED, __HIP_MEMORY_SCOPE_AGENT);
      }
    }
    int guard = 0;
    while (__hip_atomic_load(base + 288, __ATOMIC_RELAXED,
                             __HIP_MEMORY_SCOPE_AGENT) < target) {
      __builtin_amdgcn_s_sleep(2);
      if (++guard > (1 << 20)) break;   // hang guard: wrong-but-terminating
    }
    // no acquire inv: fresh h is read via system-scope loads (L2-bypassing)
  }
  __syncthreads();
}

// ---------------------------------------------------------------------------
__global__ void init_zero(u16* f0a, u16* f0b, u16* b0a, u16* b0b,
                          u16* f1a, u16* f1b, u16* b1a, u16* b1b, unsigned* bars) {
  int idx = blockIdx.x * 256 + threadIdx.x;   // grid 192*256 = 49152 = SLOT64
  if (idx < (int)SLOT16) { f0a[idx] = 0; f0b[idx] = 0; }
  b0a[idx] = 0; b0b[idx] = 0;
  f1a[idx] = 0; f1b[idx] = 0;
  b1a[idx] = 0; b1b[idx] = 0;
  if (idx < 4096) bars[idx] = 0;
}

__global__ void build_seq(const float* user, const float* sysr, const int* ulab,
                          const int* slab, u16* seqkp, int* labs) {
  int idx = blockIdx.x * 256 + threadIdx.x;   // grid 384*256 = 98304
  int t = idx / 768;
  int hh = idx - t * 768;
  float v = (t & 1) ? sysr[(t >> 1) * 768 + hh] : user[(t >> 1) * 768 + hh];
  seqkp[((size_t)(hh >> 3) * 128 + t) * 8 + (hh & 7)] = f2b(v);
  if (idx < 128) labs[idx] = (idx & 1) ? slab[idx >> 1] : ulab[idx >> 1];
}

// 12 matrices -> kp bf16 with UNIT-MAJOR row permutation (row' = unit*4+gate)
__global__ void cvt_w(const float* postWhh0, const float* priWhh0,
                      const float* postWih1, const float* priWih1,
                      const float* postWhh1, const float* priWhh1,
                      u16* W0kp, u16* W1xkp, u16* W1rkp) {
  int mat = blockIdx.y;
  int grp = mat >> 2;
  int sub = mat & 3;
  int mm = sub >> 1;
  int dirw = sub & 1;
  const float* src;
  int stride, coff;
  u16* dstb;
  if (grp == 0)      { src = mm ? priWhh0 : postWhh0; stride = 768;  coff = 0;   dstb = W0kp; }
  else if (grp == 1) { src = mm ? priWih1 : postWih1; stride = 1536; coff = 768; dstb = W1xkp; }
  else               { src = mm ? priWhh1 : postWhh1; stride = 768;  coff = 0;   dstb = W1rkp; }
  src += (size_t)dirw * 3072 * stride;
  int cid = blockIdx.x * 256 + threadIdx.x;   // grid.x = 1152 -> 294912 = 3072*96
  int g = cid / 96;
  int kb = cid - g * 96;
  int gate = g / 768;
  int unit = g - gate * 768;
  int gp = unit * 4 + gate;                   // unit-major row
  const float* s = src + (size_t)g * stride + coff + (size_t)kb * 8;
  union { u16 h[8]; int4 v; } u;
#pragma unroll
  for (int j = 0; j < 8; ++j) u.h[j] = f2b(s[j]);
  ((int4*)(dstb + (size_t)sub * WMAT))[(size_t)kb * 3072 + gp] = u.v;
}

// out[md][t][g] = A(128xK) @ W[dir](Kx3072 rows-as-gates) + b ; K=768
__global__ void __launch_bounds__(256) xw_gemm(const u16* Akp, unsigned long long Astride,
                                               const float* Wm0, const float* Wm1, int wstride,
                                               const float* bm0, const float* bm1, float* out) {
  __shared__ u16 lds[48 * 64 * 8];
  int tid = threadIdx.x;
  int lane = tid & 63;
  int wave = tid >> 6;
  int md = blockIdx.y;
  int m = md >> 1;
  int dir = md & 1;
  const u16* A = Akp + (size_t)m * Astride;
  const float* W = (m ? Wm1 : Wm0) + (size_t)dir * 3072 * wstride;
  const float* b = (m ? bm1 : bm0) + dir * 3072;
  int g0 = blockIdx.x * 64;
  int quad = lane >> 4, l15 = lane & 15;
  v4f acc[2][4];
#pragma unroll
  for (int a = 0; a < 2; ++a)
#pragma unroll
    for (int nt = 0; nt < 4; ++nt) acc[a][nt] = (v4f){0.f, 0.f, 0.f, 0.f};

  for (int hfl = 0; hfl < 2; ++hfl) {
    if (hfl) __syncthreads();
    for (int it = 0; it < 12; ++it) {
      int ck = it * 256 + tid;
      int kb = ck >> 6;
      int r = ck & 63;
      int g = g0 + r;
      const float* s = W + (size_t)g * wstride + (size_t)(hfl * 48 + kb) * 8;
      union { u16 h[8]; int4 v; } u;
#pragma unroll
      for (int j = 0; j < 8; ++j) u.h[j] = f2b(s[j]);
      *(int4*)(lds + (size_t)ck * 8) = u.v;
    }
    __syncthreads();
    for (int lt = 0; lt < 12; ++lt) {
      int kblk = (hfl * 12 + lt) * 4 + quad;
      v8s a0 = ((const v8s*)A)[(size_t)kblk * 128 + (wave * 2 + 0) * 16 + l15];
      v8s a1 = ((const v8s*)A)[(size_t)kblk * 128 + (wave * 2 + 1) * 16 + l15];
#pragma unroll
      for (int nt = 0; nt < 4; ++nt) {
        v8s bb = *(const v8s*)(lds + ((size_t)((lt * 4 + quad) * 64) + nt * 16 + l15) * 8);
        acc[0][nt] = MFMA(a0, bb, acc[0][nt]);
        acc[1][nt] = MFMA(a1, bb, acc[1][nt]);
      }
    }
  }
#pragma unroll
  for (int a = 0; a < 2; ++a)
#pragma unroll
    for (int nt = 0; nt < 4; ++nt) {
      int g = g0 + nt * 16 + l15;
      float bv = b[g];
#pragma unroll
      for (int r = 0; r < 4; ++r) {
        int trow = (wave * 2 + a) * 16 + quad * 4 + r;
        out[(size_t)(md * 128 + trow) * 3072 + g] = acc[a][nt][r] + bv;
      }
    }
}

// ---------------------------------------------------------------------------
// Phase 1: layer-0 chains. chain 0 post-bwd, 1 prior-bwd, 2 post-fwd, 3 prior-fwd
__global__ void __launch_bounds__(256, 1) phase1_k(const u16* W0kp, const float* xw0,
                                                   u16* B0, u16* F0, u16* h0f,
                                                   unsigned* bars) {
  extern __shared__ u16 ldsraw[];
  v8s* lw = (v8s*)ldsraw;                      // [96 kg8][64 rows] = 96 KB
  const int tid = threadIdx.x;
  const int w = tid >> 6, lane = tid & 63, l15 = lane & 15, l4 = lane >> 4;
  const int b = blockIdx.x;
  const int chain = (b & 7) >> 1;              // 2 XCDs per chain (round-robin)
  const int ci = ((b >> 3) << 1) | (b & 1);    // 0..47
  const int grp = ci / 6;                      // 8 barrier sub-groups of 6
  const int jb = ci << 4;                      // unit base
  const int m = chain & 1;
  const bool isf = chain >= 2;
  const int mat = m * 2 + (isf ? 0 : 1);
  unsigned* bbase = bars + chain * 512;

  { // resident Whh0 slice: contiguous rows jb*4 .. jb*4+64 (unit-major)
    const v8s* Ws = (const v8s*)(W0kp) + (size_t)mat * (WMAT / 8);
    const size_t rowb = (size_t)jb * 4;
    for (int i = 0; i < 24; ++i) {
      int idx = i * 256 + tid;
      int kg = idx >> 6, r = idx & 63;
      gl2lds16(Ws + (size_t)kg * 3072 + rowb + r, (void*)(lw + (i * 256 + (w << 6))));
    }
  }
  __syncthreads();

  const int i0 = w >> 1, j0 = w & 1;           // wave = (mt-pair, nt-pair)
  const int u0 = i0 * 8 + l4, u1 = u0 + 4;
  const int ju0 = jb + u0, ju1 = jb + u1;
  const int p0q = j0 * 32 + l15, p1q = p0q + 16;
  float c00 = 0.f, c01 = 0.f, c10 = 0.f, c11 = 0.f;
  const bool skip = isf && (j0 == 1);          // fwd: only p=0 column matters
  const bool fep  = isf && (j0 == 0) && (l15 == 0);

  for (int it = 0; it < 128; ++it) {
    const int t = isf ? it : (127 - it);       // bwd runs descending tau
    const float* xw = xw0 + (size_t)(mat * 128 + t) * 3072;
    float xi0 = xw[ju0], xf0 = xw[768 + ju0], xg0 = xw[1536 + ju0], xo0 = xw[2304 + ju0];
    float xi1 = xw[ju1], xf1 = xw[768 + ju1], xg1 = xw[1536 + ju1], xo1 = xw[2304 + ju1];
    v4f a00 = {0.f, 0.f, 0.f, 0.f}, a01 = a00, a10 = a00, a11 = a00;

    if (isf) {
      if (!skip) {
        const v8s* hs = (const v8s*)(F0 + (size_t)(m * 129 + t) * SLOT16);
#pragma unroll
        for (int kb = 0; kb < 24; ++kb) {
          int kg = kb * 4 + l4;
          v8s A0 = lw[kg * 64 + i0 * 32 + l15];
          v8s A1 = lw[kg * 64 + i0 * 32 + 16 + l15];
          v8s Bb = ld16_sys(&hs[kg * 16 + l15]);
          a00 = MFMA(A0, Bb, a00);
          a10 = MFMA(A1, Bb, a10);
        }
      }
    } else {
      const v8s* hs = (const v8s*)(B0 + (size_t)(m * 129 + t + 1) * SLOT64);
#pragma unroll
      for (int kb = 0; kb < 24; ++kb) {
        int kg = kb * 4 + l4;
        v8s A0 = lw[kg * 64 + i0 * 32 + l15];
        v8s A1 = lw[kg * 64 + i0 * 32 + 16 + l15];
        v8s Bb0 = ld16_sys(&hs[kg * 64 + p0q]);
        v8s Bb1 = ld16_sys(&hs[kg * 64 + p1q]);
        a00 = MFMA(A0, Bb0, a00);
        a01 = MFMA(A0, Bb1, a01);
        a10 = MFMA(A1, Bb0, a10);
        a11 = MFMA(A1, Bb1, a11);
      }
    }

    if (isf) {
      if (fep) {   // common forward trajectory, always-active (longest mask)
        float gi = sigf(a00[0] + xi0), gf = sigf(a00[1] + xf0);
        float gg = tanhfast(a00[2] + xg0), go = sigf(a00[3] + xo0);
        float cn = gf * c00 + gi * gg;
        float hn = go * tanhfast(cn);
        c00 = cn;
        u16 hb = f2b(hn);
        F0[(size_t)(m * 129 + t + 1) * SLOT16 + (size_t)(ju0 >> 3) * 16 * 8 + (ju0 & 7)] = hb;
        h0f[(size_t)m * SLOT128 + ((size_t)(ju0 >> 3) * 128 + t) * 8 + (ju0 & 7)] = hb;
        gi = sigf(a10[0] + xi1); gf = sigf(a10[1] + xf1);
        gg = tanhfast(a10[2] + xg1); go = sigf(a10[3] + xo1);
        cn = gf * c10 + gi * gg;
        hn = go * tanhfast(cn);
        c10 = cn;
        hb = f2b(hn);
        F0[(size_t)(m * 129 + t + 1) * SLOT16 + (size_t)(ju1 >> 3) * 16 * 8 + (ju1 & 7)] = hb;
        h0f[(size_t)m * SLOT128 + ((size_t)(ju1 >> 3) * 128 + t) * 8 + (ju1 & 7)] = hb;
      }
    } else {
      u16* hd = B0 + (size_t)(m * 129 + t) * SLOT64;
      auto epi1 = [&](const v4f& ac, float& cc, int ju, int p,
                      float xi, float xf, float xg, float xo) {
        int lenp = 2 * p + 2 - m;
        bool act = t < lenp;
        float gi = sigf(ac[0] + xi), gf = sigf(ac[1] + xf);
        float gg = tanhfast(ac[2] + xg), go = sigf(ac[3] + xo);
        float cn = gf * cc + gi * gg;
        float hn = go * tanhfast(cn);
        cc = act ? cn : 0.f;
        hd[((size_t)(ju >> 3) * 64 + p) * 8 + (ju & 7)] = f2b(act ? hn : 0.f);
      };
      epi1(a00, c00, ju0, p0q, xi0, xf0, xg0, xo0);
      epi1(a01, c01, ju0, p1q, xi0, xf0, xg0, xo0);
      epi1(a10, c10, ju1, p0q, xi1, xf1, xg1, xo1);
      epi1(a11, c11, ju1, p1q, xi1, xf1, xg1, xo1);
    }
    if (it != 127) {
      __syncthreads();
      tree_bar(bbase, grp, (unsigned)(it + 1));
    }
  }
}

// ---------------------------------------------------------------------------
// Phase 2: layer-1 chains. md 0 post-fwd1, 1 post-bwd1, 2 prior-fwd1, 3 prior-bwd1
// K = 1536: x-part (W1x @ B0[t], streamed weights) + recurrent (W1r, resident)
__global__ void __launch_bounds__(256, 1) phase2_k(const u16* W1x, const u16* W1r,
                                                   const float* xw1s, const u16* B0,
                                                   u16* F1, u16* B1, unsigned* bars) {
  extern __shared__ u16 ldsraw[];
  v8s* lwr = (v8s*)ldsraw;                 // resident W1r slice: 96 KB
  u16* bufb = ldsraw + 49152;              // 2 x 24 KB W1x ping-pong chunks
  const int tid = threadIdx.x;
  const int w = tid >> 6, lane = tid & 63, l15 = lane & 15, l4 = lane >> 4;
  const int b = blockIdx.x;
  const int md = (b & 7) >> 1;
  const int ci = ((b >> 3) << 1) | (b & 1);
  const int grp = ci / 6;
  const int jb = ci << 4;
  const int m = md >> 1, dir = md & 1;
  unsigned* bbase = bars + (4 + md) * 512;
  const size_t rowb = (size_t)jb * 4;
  const v8s* Wxs = (const v8s*)(W1x) + (size_t)md * (WMAT / 8);

  { // resident W1r slice
    const v8s* Wrs = (const v8s*)(W1r) + (size_t)md * (WMAT / 8);
    for (int i = 0; i < 24; ++i) {
      int idx = i * 256 + tid;
      int kg = idx >> 6, r = idx & 63;
      gl2lds16(Wrs + (size_t)kg * 3072 + rowb + r, (void*)(lwr + (i * 256 + (w << 6))));
    }
  }

  const int i0 = w >> 1, j0 = w & 1;
  const int u0 = i0 * 8 + l4, u1 = u0 + 4;
  const int ju0 = jb + u0, ju1 = jb + u1;
  const int p0q = j0 * 32 + l15, p1q = p0q + 16;
  float c00 = 0.f, c01 = 0.f, c10 = 0.f, c11 = 0.f;
  float he00 = 0.f, he01 = 0.f, he10 = 0.f, he11 = 0.f;   // persisted h (fwd1)

  auto stage = [&](int c, int v) {   // stage W1x chunk c (24 kg8) into buf v
#pragma unroll
    for (int q = 0; q < 6; ++q) {
      int idx = q * 256 + tid;
      int kgl = idx >> 6, r = idx & 63;
      gl2lds16(Wxs + (size_t)(c * 24 + kgl) * 3072 + rowb + r,
               (void*)(bufb + (size_t)v * 12288 + (size_t)(q * 256 + (w << 6)) * 8));
    }
  };
  stage(0, 0);
  __syncthreads();

  for (int it = 0; it < 128; ++it) {
    const int t = dir ? (127 - it) : it;
    const v8s* hx = (const v8s*)(B0 + (size_t)(m * 129 + t) * SLOT64);
    const v8s* hr = (const v8s*)(dir ? (B1 + (size_t)(m * 129 + t + 1) * SLOT64)
                                     : (F1 + (size_t)(m * 129 + t) * SLOT64));
    const float* xw = xw1s + (size_t)(md * 128 + t) * 3072;
    float xi0 = xw[ju0], xf0 = xw[768 + ju0], xg0 = xw[1536 + ju0], xo0 = xw[2304 + ju0];
    float xi1 = xw[ju1], xf1 = xw[768 + ju1], xg1 = xw[1536 + ju1], xo1 = xw[2304 + ju1];
    v4f a00 = {0.f, 0.f, 0.f, 0.f}, a01 = a00, a10 = a00, a11 = a00;

    auto rpart = [&](int k0) {   // 8 kb32 of recurrent K (h fresh -> sys loads)
#pragma unroll
      for (int k = 0; k < 8; ++k) {
        int kg = (k0 + k) * 4 + l4;
        v8s A0 = lwr[kg * 64 + i0 * 32 + l15];
        v8s A1 = lwr[kg * 64 + i0 * 32 + 16 + l15];
        v8s Bb0 = ld16_sys(&hr[kg * 64 + p0q]);
        v8s Bb1 = ld16_sys(&hr[kg * 64 + p1q]);
        a00 = MFMA(A0, Bb0, a00); a01 = MFMA(A0, Bb1, a01);
        a10 = MFMA(A1, Bb0, a10); a11 = MFMA(A1, Bb1, a11);
      }
    };
    auto xpart = [&](int c, int v) {   // 6 kb32 of x-part K (B0 stable -> L2)
      const v8s* bv = (const v8s*)(bufb + (size_t)v * 12288);
#pragma unroll
      for (int k = 0; k < 6; ++k) {
        int kgl = k * 4 + l4;
        int kg = (c * 6 + k) * 4 + l4;
        v8s A0 = bv[kgl * 64 + i0 * 32 + l15];
        v8s A1 = bv[kgl * 64 + i0 * 32 + 16 + l15];
        v8s Bb0 = hx[kg * 64 + p0q];
        v8s Bb1 = hx[kg * 64 + p1q];
        a00 = MFMA(A0, Bb0, a00); a01 = MFMA(A0, Bb1, a01);
        a10 = MFMA(A1, Bb0, a10); a11 = MFMA(A1, Bb1, a11);
      }
    };

    // ping-pong: each stage's buffer was last read one sync earlier
    stage(1, 1); rpart(0);  xpart(0, 0); __syncthreads();
    stage(2, 0); rpart(8);  xpart(1, 1); __syncthreads();
    stage(3, 1); rpart(16); xpart(2, 0); __syncthreads();
    xpart(3, 1);

    u16* hd = dir ? (B1 + (size_t)(m * 129 + t) * SLOT64)
                  : (F1 + (size_t)(m * 129 + t + 1) * SLOT64);
    auto epi = [&](const v4f& ac, float& cc, float& he, int ju, int p,
                   float xi, float xf, float xg, float xo) {
      int lenp = 2 * p + 2 - m;
      bool act = t < lenp;
      float gi = sigf(ac[0] + xi), gf = sigf(ac[1] + xf);
      float gg = tanhfast(ac[2] + xg), go = sigf(ac[3] + xo);
      float cn = gf * cc + gi * gg;
      float hn = go * tanhfast(cn);
      float hv;
      if (dir) { hv = act ? hn : 0.f;  cc = act ? cn : 0.f; }
      else     { hv = act ? hn : he;   cc = act ? cn : cc;  }
      he = hv;
      hd[((size_t)(ju >> 3) * 64 + p) * 8 + (ju & 7)] = f2b(hv);
    };
    epi(a00, c00, he00, ju0, p0q, xi0, xf0, xg0, xo0);
    epi(a01, c01, he01, ju0, p1q, xi0, xf0, xg0, xo0);
    epi(a10, c10, he10, ju1, p0q, xi1, xf1, xg1, xo1);
    epi(a11, c11, he11, ju1, p1q, xi1, xf1, xg1, xo1);

    if (it != 127) {
      __syncthreads();
      stage(0, 0);               // next-iter chunk0; overlaps barrier wait
      tree_bar(bbase, grp, (unsigned)(it + 1));
    }
  }
}

// ---------------------------------------------------------------------------
__global__ void __launch_bounds__(256) em_k(const u16* F1, const u16* B1,
                                            const float* pW0, const float* pb0,
                                            const float* pW1, const float* pb1, float* em) {
  int wid = blockIdx.x * 4 + (threadIdx.x >> 6);   // grid 4096 -> 16384 waves
  int lane = threadIdx.x & 63;
  int m = wid >> 13;
  int rem = wid & 8191;
  int p = rem >> 7;
  int t = rem & 127;
  const u16* hf = F1 + (size_t)(m * 129 + t + 1) * SLOT64;
  const u16* hb = B1 + (size_t)(m * 129 + t) * SLOT64;
  const float* Pw = m ? pW1 : pW0;
  const float* Pb = m ? pb1 : pb0;
  float s0 = 0.f, s1 = 0.f;
#pragma unroll
  for (int i = 0; i < 12; ++i) {
    int j = i * 64 + lane;
    size_t o = ((size_t)(j >> 3) * 64 + p) * 8 + (j & 7);
    float vf = b2f(hf[o]);
    float vb = b2f(hb[o]);
    s0 += Pw[j] * vf + Pw[768 + j] * vb;
    s1 += Pw[1536 + j] * vf + Pw[2304 + j] * vb;
  }
  for (int off = 32; off; off >>= 1) {
    s0 += __shfl_down(s0, off, 64);
    s1 += __shfl_down(s1, off, 64);
  }
  if (lane == 0) {
    em[((size_t)(m * 64 + p) * 128 + t) * 2 + 0] = s0 + Pb[0];
    em[((size_t)(m * 64 + p) * 128 + t) * 2 + 1] = s1 + Pb[1];
  }
}

__global__ void final_k(const float* em, const int* labs, const float* T, float* out) {
  int p = threadIdx.x;   // 64 threads, 1 wave
  const float* emP = em + (size_t)p * 128 * 2;
  int lp = 2 * p + 2;
  float T00 = T[0], T01 = T[1], T10 = T[2], T11 = T[3];
  int prevlab = labs[0];
  float gold = emP[prevlab];
  for (int t = 1; t < lp; ++t) {
    int lb = labs[t];
    gold += emP[t * 2 + lb] + (prevlab ? (lb ? T11 : T10) : (lb ? T01 : T00));
    prevlab = lb;
  }
  float a0 = emP[0], a1 = emP[1];
  for (int t = 1; t < lp; ++t) {
    float n0 = lse2(a0 + T00, a1 + T10) + emP[t * 2];
    float n1 = lse2(a0 + T01, a1 + T11) + emP[t * 2 + 1];
    a0 = n0;
    a1 = n1;
  }
  float crf = lse2(a0, a1) - gold;
  const float* emR = em + (size_t)(64 + p) * 128 * 2;
  int lpr = 2 * p + 1;
  float d0 = emR[(lpr - 1) * 2 + 0] - emP[(lp - 1) * 2 + 0];
  float d1 = emR[(lpr - 1) * 2 + 1] - emP[(lp - 1) * 2 + 1];
  float mse = d0 * d0 + d1 * d1;
  for (int off = 32; off; off >>= 1) {
    crf += __shfl_down(crf, off, 64);
    mse += __shfl_down(mse, off, 64);
  }
  if (p == 0) {
    float lc = crf / 64.f;
    float lm = mse / 128.f;
    out[0] = lc;
    out[1] = lm;
    out[2] = lc + 0.1f * lm;
  }
}

// ---------------------------------------------------------------------------
extern "C" void kernel_launch(void* const* d_in, const int* in_sizes, int n_in,
                              void* d_out, int out_size, void* d_ws, size_t ws_size,
                              hipStream_t stream) {
  (void)in_sizes; (void)n_in; (void)out_size;
  if (ws_size < WS_NEED) return;   // diagnosable: output stays poisoned

  const float* user     = (const float*)d_in[0];
  const float* sysr     = (const float*)d_in[1];
  const float* postWih0 = (const float*)d_in[2];
  const float* postWhh0 = (const float*)d_in[3];
  const float* postb0   = (const float*)d_in[4];
  const float* postWih1 = (const float*)d_in[5];
  const float* postWhh1 = (const float*)d_in[6];
  const float* postb1   = (const float*)d_in[7];
  const float* priWih0  = (const float*)d_in[8];
  const float* priWhh0  = (const float*)d_in[9];
  const float* prib0    = (const float*)d_in[10];
  const float* priWih1  = (const float*)d_in[11];
  const float* priWhh1  = (const float*)d_in[12];
  const float* prib1    = (const float*)d_in[13];
  const float* postPW   = (const float*)d_in[14];
  const float* postPb   = (const float*)d_in[15];
  const float* priPW    = (const float*)d_in[16];
  const float* priPb    = (const float*)d_in[17];
  const float* trans    = (const float*)d_in[18];
  const int*   ulab     = (const int*)d_in[19];
  const int*   slab     = (const int*)d_in[20];
  float* out = (float*)d_out;

  char* wsb = (char*)d_ws;
  float* em    = (float*)(wsb + OFF_EM);
  float* xw0   = (float*)(wsb + OFF_XW0);
  float* xw1s  = (float*)(wsb + OFF_XW1);
  u16* seqkp   = (u16*)(wsb + OFF_SEQ);
  int* labs    = (int*)(wsb + OFF_LABS);
  unsigned* bars = (unsigned*)(wsb + OFF_BAR);
  u16* W0kp    = (u16*)(wsb + OFF_W0);
  u16* W1xkp   = (u16*)(wsb + OFF_W1X);
  u16* W1rkp   = (u16*)(wsb + OFF_W1R);
  u16* F0      = (u16*)(wsb + OFF_F0);
  u16* h0f     = (u16*)(wsb + OFF_H0F);
  u16* B0      = (u16*)(wsb + OFF_B0);
  u16* F1      = (u16*)(wsb + OFF_F1);
  u16* B1      = (u16*)(wsb + OFF_B1);

  static bool attr_done = false;
  if (!attr_done) {
    (void)hipFuncSetAttribute(reinterpret_cast<const void*>(phase1_k),
                              hipFuncAttributeMaxDynamicSharedMemorySize, 98304);
    (void)hipFuncSetAttribute(reinterpret_cast<const void*>(phase2_k),
                              hipFuncAttributeMaxDynamicSharedMemorySize, 147456);
    attr_done = true;
  }

  init_zero<<<192, 256, 0, stream>>>(
      F0, F0 + (size_t)129 * SLOT16,
      B0 + (size_t)128 * SLOT64, B0 + (size_t)(129 + 128) * SLOT64,
      F1, F1 + (size_t)129 * SLOT64,
      B1 + (size_t)128 * SLOT64, B1 + (size_t)(129 + 128) * SLOT64, bars);

  build_seq<<<384, 256, 0, stream>>>(user, sysr, ulab, slab, seqkp, labs);

  cvt_w<<<dim3(1152, 12), 256, 0, stream>>>(postWhh0, priWhh0, postWih1, priWih1,
                                            postWhh1, priWhh1, W0kp, W1xkp, W1rkp);

  xw_gemm<<<dim3(48, 4), 256, 0, stream>>>(seqkp, 0ULL, postWih0, priWih0, 768,
                                           postb0, prib0, xw0);

  phase1_k<<<192, 256, 98304, stream>>>(W0kp, xw0, B0, F0, h0f, bars);

  xw_gemm<<<dim3(48, 4), 256, 0, stream>>>(h0f, (unsigned long long)SLOT128,
                                           postWih1, priWih1, 1536, postb1, prib1, xw1s);

  phase2_k<<<192, 256, 147456, stream>>>(W1xkp, W1rkp, xw1s, B0, F1, B1, bars);

  em_k<<<4096, 256, 0, stream>>>(F1, B1, postPW, postPb, priPW, priPb, em);

  final_k<<<1, 64, 0, stream>>>(em, labs, trans, out);
}

// Round 4
// 3670.103 us; speedup vs baseline: 1.2525x; 1.2525x over previous
//
#include <hip/hip_runtime.h>

// ---------------------------------------------------------------------------
// VanillaCRF forward on MI355X — persistent-chain version, write-through-h
// edition.
//
// Compute/dataflow identical to the verified round-2 kernel (absmax 0.0),
// except phase2 accumulates xpart chunks before rpart (fp reorder only).
// Sync protocol redesigned from rounds 2/3 evidence:
//   - h STORES are system-scope write-through (global_store_short sc0 sc1):
//     2 KB/block/iter goes straight to the IC. No wbl2, no inv needed.
//   - h READS are plain loads: slots are written-before-first-read and L2s
//     are clean at dispatch start, so no staleness; 24 blocks/XCD share each
//     96 KB h slot through their L2 (round-3's sys-loads paid IC latency
//     per block and regressed).
//   - Barrier is pure monotonic tree atomics (8 sub-lines x 6 -> top -> gen),
//     split into signal (after stores drain) and wait (just before the
//     h-dependent compute). Phase2 overlaps stage+xpart with the wait.
// ---------------------------------------------------------------------------

typedef short v8s __attribute__((ext_vector_type(8)));
typedef float v4f __attribute__((ext_vector_type(4)));
typedef unsigned short u16;

#define MFMA(a, b, c) __builtin_amdgcn_mfma_f32_16x16x32_bf16((a), (b), (c), 0, 0, 0)

static constexpr size_t WMAT    = (size_t)96 * 3072 * 8;   // u16 elems per 3072x768 kp matrix
static constexpr size_t SLOT16  = (size_t)96 * 16 * 8;
static constexpr size_t SLOT64  = (size_t)96 * 64 * 8;
static constexpr size_t SLOT128 = (size_t)96 * 128 * 8;

static constexpr size_t OFF_EM   = 0;
static constexpr size_t SZ_EM    = (size_t)2 * 64 * 128 * 2 * 4;
static constexpr size_t OFF_XW0  = OFF_EM + SZ_EM;
static constexpr size_t SZ_XW    = (size_t)4 * 128 * 3072 * 4;
static constexpr size_t OFF_XW1  = OFF_XW0 + SZ_XW;
static constexpr size_t OFF_SEQ  = OFF_XW1 + SZ_XW;
static constexpr size_t SZ_SEQ   = SLOT128 * 2;
static constexpr size_t OFF_LABS = OFF_SEQ + SZ_SEQ;     // 512 B
static constexpr size_t OFF_BAR  = OFF_LABS + 512;       // 16 KB (8 chains x 512 u32)
static constexpr size_t SZ_BAR   = 16384;
static constexpr size_t OFF_W0   = OFF_BAR + SZ_BAR;
static constexpr size_t SZ_W4    = (size_t)4 * WMAT * 2;
static constexpr size_t OFF_W1X  = OFF_W0 + SZ_W4;
static constexpr size_t OFF_W1R  = OFF_W1X + SZ_W4;
static constexpr size_t OFF_F0   = OFF_W1R + SZ_W4;
static constexpr size_t SZ_F0    = (size_t)2 * 129 * SLOT16 * 2;
static constexpr size_t OFF_H0F  = OFF_F0 + SZ_F0;
static constexpr size_t SZ_H0F   = (size_t)2 * SLOT128 * 2;
static constexpr size_t OFF_B0   = OFF_H0F + SZ_H0F;
static constexpr size_t SZ_S64   = (size_t)2 * 129 * SLOT64 * 2;
static constexpr size_t OFF_F1   = OFF_B0 + SZ_S64;
static constexpr size_t OFF_B1   = OFF_F1 + SZ_S64;
static constexpr size_t WS_NEED  = OFF_B1 + SZ_S64;      // ~145 MB

static __device__ __forceinline__ u16 f2b(float f) {
  unsigned int u = __float_as_uint(f);
  unsigned int r = (u + 0x7FFFu + ((u >> 16) & 1u)) >> 16;   // RNE
  return (u16)r;
}
static __device__ __forceinline__ float b2f(u16 u) {
  return __uint_as_float(((unsigned int)u) << 16);
}
static __device__ __forceinline__ float sigf(float x) {
  return 1.0f / (1.0f + __expf(-x));
}
static __device__ __forceinline__ float tanhfast(float x) {
  return 1.0f - 2.0f / (__expf(2.0f * x) + 1.0f);
}
static __device__ __forceinline__ float lse2(float a, float b) {
  float mx = fmaxf(a, b);
  return mx + __logf(__expf(a - mx) + __expf(b - mx));
}

// async global->LDS, 16B per lane; LDS base wave-uniform, +lane*16 implicit
static __device__ __forceinline__ void gl2lds16(const void* g, void* l) {
  __builtin_amdgcn_global_load_lds((const __attribute__((address_space(1))) unsigned int*)g,
                                   (__attribute__((address_space(3))) unsigned int*)l,
                                   16, 0, 0);
}

// system-scope write-through 2-byte store: bypass L1/L2, land in the IC.
// vmcnt tracks completion; the pre-barrier s_waitcnt vmcnt(0) drains it.
static __device__ __forceinline__ void st2_sys(u16* p, u16 v) {
  unsigned int vv = v;
  asm volatile("global_store_short %0, %1, off sc0 sc1"
               :: "v"(p), "v"(vv) : "memory");
}

// ---------------------------------------------------------------------------
// Monotonic 2-level tree barrier (pure atomics, no cache maintenance).
// base: per-chain region of 512 u32 (2 KB).
//   sub-line g (g=0..7): base + g*32 ; top: base + 256 ; gen: base + 288
// bar_signal: caller guarantees all waves' stores drained (post-__syncthreads).
// bar_wait(target): blocks until gen >= target, then __syncthreads.
static __device__ __forceinline__ void bar_signal(unsigned* base, int grp) {
  if (threadIdx.x == 0) {
    asm volatile("s_waitcnt vmcnt(0)" ::: "memory");
    unsigned o1 = __hip_atomic_fetch_add(base + grp * 32, 1u,
                                         __ATOMIC_RELAXED, __HIP_MEMORY_SCOPE_AGENT);
    if ((o1 % 6u) == 5u) {   // 6th arrival on this sub-line this round
      unsigned o2 = __hip_atomic_fetch_add(base + 256, 1u,
                                           __ATOMIC_RELAXED, __HIP_MEMORY_SCOPE_AGENT);
      if ((o2 % 8u) == 7u) { // 8th sub-group leader this round
        __hip_atomic_fetch_add(base + 288, 1u,
                               __ATOMIC_RELAXED, __HIP_MEMORY_SCOPE_AGENT);
      }
    }
  }
}
static __device__ __forceinline__ void bar_wait(unsigned* base, unsigned target) {
  if (threadIdx.x == 0) {
    int guard = 0;
    while (__hip_atomic_load(base + 288, __ATOMIC_RELAXED,
                             __HIP_MEMORY_SCOPE_AGENT) < target) {
      __builtin_amdgcn_s_sleep(1);
      if (++guard > (1 << 21)) break;   // hang guard: wrong-but-terminating
    }
  }
  __syncthreads();
}

// ---------------------------------------------------------------------------
__global__ void init_zero(u16* f0a, u16* f0b, u16* b0a, u16* b0b,
                          u16* f1a, u16* f1b, u16* b1a, u16* b1b, unsigned* bars) {
  int idx = blockIdx.x * 256 + threadIdx.x;   // grid 192*256 = 49152 = SLOT64
  if (idx < (int)SLOT16) { f0a[idx] = 0; f0b[idx] = 0; }
  b0a[idx] = 0; b0b[idx] = 0;
  f1a[idx] = 0; f1b[idx] = 0;
  b1a[idx] = 0; b1b[idx] = 0;
  if (idx < 4096) bars[idx] = 0;
}

__global__ void build_seq(const float* user, const float* sysr, const int* ulab,
                          const int* slab, u16* seqkp, int* labs) {
  int idx = blockIdx.x * 256 + threadIdx.x;   // grid 384*256 = 98304
  int t = idx / 768;
  int hh = idx - t * 768;
  float v = (t & 1) ? sysr[(t >> 1) * 768 + hh] : user[(t >> 1) * 768 + hh];
  seqkp[((size_t)(hh >> 3) * 128 + t) * 8 + (hh & 7)] = f2b(v);
  if (idx < 128) labs[idx] = (idx & 1) ? slab[idx >> 1] : ulab[idx >> 1];
}

// 12 matrices -> kp bf16 with UNIT-MAJOR row permutation (row' = unit*4+gate)
__global__ void cvt_w(const float* postWhh0, const float* priWhh0,
                      const float* postWih1, const float* priWih1,
                      const float* postWhh1, const float* priWhh1,
                      u16* W0kp, u16* W1xkp, u16* W1rkp) {
  int mat = blockIdx.y;
  int grp = mat >> 2;
  int sub = mat & 3;
  int mm = sub >> 1;
  int dirw = sub & 1;
  const float* src;
  int stride, coff;
  u16* dstb;
  if (grp == 0)      { src = mm ? priWhh0 : postWhh0; stride = 768;  coff = 0;   dstb = W0kp; }
  else if (grp == 1) { src = mm ? priWih1 : postWih1; stride = 1536; coff = 768; dstb = W1xkp; }
  else               { src = mm ? priWhh1 : postWhh1; stride = 768;  coff = 0;   dstb = W1rkp; }
  src += (size_t)dirw * 3072 * stride;
  int cid = blockIdx.x * 256 + threadIdx.x;   // grid.x = 1152 -> 294912 = 3072*96
  int g = cid / 96;
  int kb = cid - g * 96;
  int gate = g / 768;
  int unit = g - gate * 768;
  int gp = unit * 4 + gate;                   // unit-major row
  const float* s = src + (size_t)g * stride + coff + (size_t)kb * 8;
  union { u16 h[8]; int4 v; } u;
#pragma unroll
  for (int j = 0; j < 8; ++j) u.h[j] = f2b(s[j]);
  ((int4*)(dstb + (size_t)sub * WMAT))[(size_t)kb * 3072 + gp] = u.v;
}

// out[md][t][g] = A(128xK) @ W[dir](Kx3072 rows-as-gates) + b ; K=768
__global__ void __launch_bounds__(256) xw_gemm(const u16* Akp, unsigned long long Astride,
                                               const float* Wm0, const float* Wm1, int wstride,
                                               const float* bm0, const float* bm1, float* out) {
  __shared__ u16 lds[48 * 64 * 8];
  int tid = threadIdx.x;
  int lane = tid & 63;
  int wave = tid >> 6;
  int md = blockIdx.y;
  int m = md >> 1;
  int dir = md & 1;
  const u16* A = Akp + (size_t)m * Astride;
  const float* W = (m ? Wm1 : Wm0) + (size_t)dir * 3072 * wstride;
  const float* b = (m ? bm1 : bm0) + dir * 3072;
  int g0 = blockIdx.x * 64;
  int quad = lane >> 4, l15 = lane & 15;
  v4f acc[2][4];
#pragma unroll
  for (int a = 0; a < 2; ++a)
#pragma unroll
    for (int nt = 0; nt < 4; ++nt) acc[a][nt] = (v4f){0.f, 0.f, 0.f, 0.f};

  for (int hfl = 0; hfl < 2; ++hfl) {
    if (hfl) __syncthreads();
    for (int it = 0; it < 12; ++it) {
      int ck = it * 256 + tid;
      int kb = ck >> 6;
      int r = ck & 63;
      int g = g0 + r;
      const float* s = W + (size_t)g * wstride + (size_t)(hfl * 48 + kb) * 8;
      union { u16 h[8]; int4 v; } u;
#pragma unroll
      for (int j = 0; j < 8; ++j) u.h[j] = f2b(s[j]);
      *(int4*)(lds + (size_t)ck * 8) = u.v;
    }
    __syncthreads();
    for (int lt = 0; lt < 12; ++lt) {
      int kblk = (hfl * 12 + lt) * 4 + quad;
      v8s a0 = ((const v8s*)A)[(size_t)kblk * 128 + (wave * 2 + 0) * 16 + l15];
      v8s a1 = ((const v8s*)A)[(size_t)kblk * 128 + (wave * 2 + 1) * 16 + l15];
#pragma unroll
      for (int nt = 0; nt < 4; ++nt) {
        v8s bb = *(const v8s*)(lds + ((size_t)((lt * 4 + quad) * 64) + nt * 16 + l15) * 8);
        acc[0][nt] = MFMA(a0, bb, acc[0][nt]);
        acc[1][nt] = MFMA(a1, bb, acc[1][nt]);
      }
    }
  }
#pragma unroll
  for (int a = 0; a < 2; ++a)
#pragma unroll
    for (int nt = 0; nt < 4; ++nt) {
      int g = g0 + nt * 16 + l15;
      float bv = b[g];
#pragma unroll
      for (int r = 0; r < 4; ++r) {
        int trow = (wave * 2 + a) * 16 + quad * 4 + r;
        out[(size_t)(md * 128 + trow) * 3072 + g] = acc[a][nt][r] + bv;
      }
    }
}

// ---------------------------------------------------------------------------
// Phase 1: layer-0 chains. chain 0 post-bwd, 1 prior-bwd, 2 post-fwd, 3 prior-fwd
__global__ void __launch_bounds__(256, 1) phase1_k(const u16* W0kp, const float* xw0,
                                                   u16* B0, u16* F0, u16* h0f,
                                                   unsigned* bars) {
  extern __shared__ u16 ldsraw[];
  v8s* lw = (v8s*)ldsraw;                      // [96 kg8][64 rows] = 96 KB
  const int tid = threadIdx.x;
  const int w = tid >> 6, lane = tid & 63, l15 = lane & 15, l4 = lane >> 4;
  const int b = blockIdx.x;
  const int chain = (b & 7) >> 1;              // 2 XCDs per chain (round-robin)
  const int ci = ((b >> 3) << 1) | (b & 1);    // 0..47
  const int grp = ci / 6;                      // 8 barrier sub-groups of 6
  const int jb = ci << 4;                      // unit base
  const int m = chain & 1;
  const bool isf = chain >= 2;
  const int mat = m * 2 + (isf ? 0 : 1);
  unsigned* bbase = bars + chain * 512;

  { // resident Whh0 slice: contiguous rows jb*4 .. jb*4+64 (unit-major)
    const v8s* Ws = (const v8s*)(W0kp) + (size_t)mat * (WMAT / 8);
    const size_t rowb = (size_t)jb * 4;
    for (int i = 0; i < 24; ++i) {
      int idx = i * 256 + tid;
      int kg = idx >> 6, r = idx & 63;
      gl2lds16(Ws + (size_t)kg * 3072 + rowb + r, (void*)(lw + (i * 256 + (w << 6))));
    }
  }
  __syncthreads();

  const int i0 = w >> 1, j0 = w & 1;           // wave = (mt-pair, nt-pair)
  const int u0 = i0 * 8 + l4, u1 = u0 + 4;
  const int ju0 = jb + u0, ju1 = jb + u1;
  const int p0q = j0 * 32 + l15, p1q = p0q + 16;
  float c00 = 0.f, c01 = 0.f, c10 = 0.f, c11 = 0.f;
  const bool skip = isf && (j0 == 1);          // fwd: only p=0 column matters
  const bool fep  = isf && (j0 == 0) && (l15 == 0);

  for (int it = 0; it < 128; ++it) {
    const int t = isf ? it : (127 - it);       // bwd runs descending tau
    const float* xw = xw0 + (size_t)(mat * 128 + t) * 3072;
    // stable loads issue before the wait (overlap poll latency)
    float xi0 = xw[ju0], xf0 = xw[768 + ju0], xg0 = xw[1536 + ju0], xo0 = xw[2304 + ju0];
    float xi1 = xw[ju1], xf1 = xw[768 + ju1], xg1 = xw[1536 + ju1], xo1 = xw[2304 + ju1];
    v4f a00 = {0.f, 0.f, 0.f, 0.f}, a01 = a00, a10 = a00, a11 = a00;

    if (it) bar_wait(bbase, (unsigned)it);     // peers' h(step it-1) visible

    if (isf) {
      if (!skip) {
        const v8s* hs = (const v8s*)(F0 + (size_t)(m * 129 + t) * SLOT16);
#pragma unroll
        for (int kb = 0; kb < 24; ++kb) {
          int kg = kb * 4 + l4;
          v8s A0 = lw[kg * 64 + i0 * 32 + l15];
          v8s A1 = lw[kg * 64 + i0 * 32 + 16 + l15];
          v8s Bb = hs[kg * 16 + l15];
          a00 = MFMA(A0, Bb, a00);
          a10 = MFMA(A1, Bb, a10);
        }
      }
    } else {
      const v8s* hs = (const v8s*)(B0 + (size_t)(m * 129 + t + 1) * SLOT64);
#pragma unroll
      for (int kb = 0; kb < 24; ++kb) {
        int kg = kb * 4 + l4;
        v8s A0 = lw[kg * 64 + i0 * 32 + l15];
        v8s A1 = lw[kg * 64 + i0 * 32 + 16 + l15];
        v8s Bb0 = hs[kg * 64 + p0q];
        v8s Bb1 = hs[kg * 64 + p1q];
        a00 = MFMA(A0, Bb0, a00);
        a01 = MFMA(A0, Bb1, a01);
        a10 = MFMA(A1, Bb0, a10);
        a11 = MFMA(A1, Bb1, a11);
      }
    }

    if (isf) {
      if (fep) {   // common forward trajectory, always-active (longest mask)
        float gi = sigf(a00[0] + xi0), gf = sigf(a00[1] + xf0);
        float gg = tanhfast(a00[2] + xg0), go = sigf(a00[3] + xo0);
        float cn = gf * c00 + gi * gg;
        float hn = go * tanhfast(cn);
        c00 = cn;
        u16 hb = f2b(hn);
        st2_sys(F0 + (size_t)(m * 129 + t + 1) * SLOT16 + (size_t)(ju0 >> 3) * 16 * 8 + (ju0 & 7), hb);
        h0f[(size_t)m * SLOT128 + ((size_t)(ju0 >> 3) * 128 + t) * 8 + (ju0 & 7)] = hb;
        gi = sigf(a10[0] + xi1); gf = sigf(a10[1] + xf1);
        gg = tanhfast(a10[2] + xg1); go = sigf(a10[3] + xo1);
        cn = gf * c10 + gi * gg;
        hn = go * tanhfast(cn);
        c10 = cn;
        hb = f2b(hn);
        st2_sys(F0 + (size_t)(m * 129 + t + 1) * SLOT16 + (size_t)(ju1 >> 3) * 16 * 8 + (ju1 & 7), hb);
        h0f[(size_t)m * SLOT128 + ((size_t)(ju1 >> 3) * 128 + t) * 8 + (ju1 & 7)] = hb;
      }
    } else {
      u16* hd = B0 + (size_t)(m * 129 + t) * SLOT64;
      auto epi1 = [&](const v4f& ac, float& cc, int ju, int p,
                      float xi, float xf, float xg, float xo) {
        int lenp = 2 * p + 2 - m;
        bool act = t < lenp;
        float gi = sigf(ac[0] + xi), gf = sigf(ac[1] + xf);
        float gg = tanhfast(ac[2] + xg), go = sigf(ac[3] + xo);
        float cn = gf * cc + gi * gg;
        float hn = go * tanhfast(cn);
        cc = act ? cn : 0.f;
        st2_sys(hd + ((size_t)(ju >> 3) * 64 + p) * 8 + (ju & 7), f2b(act ? hn : 0.f));
      };
      epi1(a00, c00, ju0, p0q, xi0, xf0, xg0, xo0);
      epi1(a01, c01, ju0, p1q, xi0, xf0, xg0, xo0);
      epi1(a10, c10, ju1, p0q, xi1, xf1, xg1, xo1);
      epi1(a11, c11, ju1, p1q, xi1, xf1, xg1, xo1);
    }
    __syncthreads();                 // drains every wave's stores (vmcnt 0)
    if (it != 127) bar_signal(bbase, grp);
  }
}

// ---------------------------------------------------------------------------
// Phase 2: layer-1 chains. md 0 post-fwd1, 1 post-bwd1, 2 prior-fwd1, 3 prior-bwd1
// K = 1536: x-part (W1x @ B0[t], streamed weights) + recurrent (W1r, resident)
// Per iter: stage+xpart (stable inputs) overlap the barrier wait; rpart
// (h-dependent) runs after bar_wait.
__global__ void __launch_bounds__(256, 1) phase2_k(const u16* W1x, const u16* W1r,
                                                   const float* xw1s, const u16* B0,
                                                   u16* F1, u16* B1, unsigned* bars) {
  extern __shared__ u16 ldsraw[];
  v8s* lwr = (v8s*)ldsraw;                 // resident W1r slice: 96 KB
  u16* bufb = ldsraw + 49152;              // 2 x 24 KB W1x ping-pong chunks
  const int tid = threadIdx.x;
  const int w = tid >> 6, lane = tid & 63, l15 = lane & 15, l4 = lane >> 4;
  const int b = blockIdx.x;
  const int md = (b & 7) >> 1;
  const int ci = ((b >> 3) << 1) | (b & 1);
  const int grp = ci / 6;
  const int jb = ci << 4;
  const int m = md >> 1, dir = md & 1;
  unsigned* bbase = bars + (4 + md) * 512;
  const size_t rowb = (size_t)jb * 4;
  const v8s* Wxs = (const v8s*)(W1x) + (size_t)md * (WMAT / 8);

  { // resident W1r slice
    const v8s* Wrs = (const v8s*)(W1r) + (size_t)md * (WMAT / 8);
    for (int i = 0; i < 24; ++i) {
      int idx = i * 256 + tid;
      int kg = idx >> 6, r = idx & 63;
      gl2lds16(Wrs + (size_t)kg * 3072 + rowb + r, (void*)(lwr + (i * 256 + (w << 6))));
    }
  }

  const int i0 = w >> 1, j0 = w & 1;
  const int u0 = i0 * 8 + l4, u1 = u0 + 4;
  const int ju0 = jb + u0, ju1 = jb + u1;
  const int p0q = j0 * 32 + l15, p1q = p0q + 16;
  float c00 = 0.f, c01 = 0.f, c10 = 0.f, c11 = 0.f;
  float he00 = 0.f, he01 = 0.f, he10 = 0.f, he11 = 0.f;   // persisted h (fwd1)

  auto stage = [&](int c, int v) {   // stage W1x chunk c (24 kg8) into buf v
#pragma unroll
    for (int q = 0; q < 6; ++q) {
      int idx = q * 256 + tid;
      int kgl = idx >> 6, r = idx & 63;
      gl2lds16(Wxs + (size_t)(c * 24 + kgl) * 3072 + rowb + r,
               (void*)(bufb + (size_t)v * 12288 + (size_t)(q * 256 + (w << 6)) * 8));
    }
  };
  stage(0, 0);
  __syncthreads();

  for (int it = 0; it < 128; ++it) {
    const int t = dir ? (127 - it) : it;
    const v8s* hx = (const v8s*)(B0 + (size_t)(m * 129 + t) * SLOT64);
    const v8s* hr = (const v8s*)(dir ? (B1 + (size_t)(m * 129 + t + 1) * SLOT64)
                                     : (F1 + (size_t)(m * 129 + t) * SLOT64));
    const float* xw = xw1s + (size_t)(md * 128 + t) * 3072;
    float xi0 = xw[ju0], xf0 = xw[768 + ju0], xg0 = xw[1536 + ju0], xo0 = xw[2304 + ju0];
    float xi1 = xw[ju1], xf1 = xw[768 + ju1], xg1 = xw[1536 + ju1], xo1 = xw[2304 + ju1];
    v4f a00 = {0.f, 0.f, 0.f, 0.f}, a01 = a00, a10 = a00, a11 = a00;

    auto rpart = [&](int k0) {   // 8 kb32 of recurrent K (fresh h, plain loads)
#pragma unroll
      for (int k = 0; k < 8; ++k) {
        int kg = (k0 + k) * 4 + l4;
        v8s A0 = lwr[kg * 64 + i0 * 32 + l15];
        v8s A1 = lwr[kg * 64 + i0 * 32 + 16 + l15];
        v8s Bb0 = hr[kg * 64 + p0q];
        v8s Bb1 = hr[kg * 64 + p1q];
        a00 = MFMA(A0, Bb0, a00); a01 = MFMA(A0, Bb1, a01);
        a10 = MFMA(A1, Bb0, a10); a11 = MFMA(A1, Bb1, a11);
      }
    };
    auto xpart = [&](int c, int v) {   // 6 kb32 of x-part K (stable inputs)
      const v8s* bv = (const v8s*)(bufb + (size_t)v * 12288);
#pragma unroll
      for (int k = 0; k < 6; ++k) {
        int kgl = k * 4 + l4;
        int kg = (c * 6 + k) * 4 + l4;
        v8s A0 = bv[kgl * 64 + i0 * 32 + l15];
        v8s A1 = bv[kgl * 64 + i0 * 32 + 16 + l15];
        v8s Bb0 = hx[kg * 64 + p0q];
        v8s Bb1 = hx[kg * 64 + p1q];
        a00 = MFMA(A0, Bb0, a00); a01 = MFMA(A0, Bb1, a01);
        a10 = MFMA(A1, Bb0, a10); a11 = MFMA(A1, Bb1, a11);
      }
    };

    // stable work first (overlaps peers' straggle + barrier propagation)
    stage(1, 1); xpart(0, 0); __syncthreads();
    stage(2, 0); xpart(1, 1); __syncthreads();
    stage(3, 1); xpart(2, 0); __syncthreads();
    xpart(3, 1);
    if (it) bar_wait(bbase, (unsigned)it);   // peers' h(step it-1) visible
    rpart(0); rpart(8); rpart(16);

    u16* hd = dir ? (B1 + (size_t)(m * 129 + t) * SLOT64)
                  : (F1 + (size_t)(m * 129 + t + 1) * SLOT64);
    auto epi = [&](const v4f& ac, float& cc, float& he, int ju, int p,
                   float xi, float xf, float xg, float xo) {
      int lenp = 2 * p + 2 - m;
      bool act = t < lenp;
      float gi = sigf(ac[0] + xi), gf = sigf(ac[1] + xf);
      float gg = tanhfast(ac[2] + xg), go = sigf(ac[3] + xo);
      float cn = gf * cc + gi * gg;
      float hn = go * tanhfast(cn);
      float hv;
      if (dir) { hv = act ? hn : 0.f;  cc = act ? cn : 0.f; }
      else     { hv = act ? hn : he;   cc = act ? cn : cc;  }
      he = hv;
      st2_sys(hd + ((size_t)(ju >> 3) * 64 + p) * 8 + (ju & 7), f2b(hv));
    };
    epi(a00, c00, he00, ju0, p0q, xi0, xf0, xg0, xo0);
    epi(a01, c01, he01, ju0, p1q, xi0, xf0, xg0, xo0);
    epi(a10, c10, he10, ju1, p0q, xi1, xf1, xg1, xo1);
    epi(a11, c11, he11, ju1, p1q, xi1, xf1, xg1, xo1);

    stage(0, 0);                 // next-iter chunk0 (buf0 free since sync #3)
    __syncthreads();             // drains stores + stage; blocks LDS hazards
    if (it != 127) bar_signal(bbase, grp);
  }
}

// ---------------------------------------------------------------------------
__global__ void __launch_bounds__(256) em_k(const u16* F1, const u16* B1,
                                            const float* pW0, const float* pb0,
                                            const float* pW1, const float* pb1, float* em) {
  int wid = blockIdx.x * 4 + (threadIdx.x >> 6);   // grid 4096 -> 16384 waves
  int lane = threadIdx.x & 63;
  int m = wid >> 13;
  int rem = wid & 8191;
  int p = rem >> 7;
  int t = rem & 127;
  const u16* hf = F1 + (size_t)(m * 129 + t + 1) * SLOT64;
  const u16* hb = B1 + (size_t)(m * 129 + t) * SLOT64;
  const float* Pw = m ? pW1 : pW0;
  const float* Pb = m ? pb1 : pb0;
  float s0 = 0.f, s1 = 0.f;
#pragma unroll
  for (int i = 0; i < 12; ++i) {
    int j = i * 64 + lane;
    size_t o = ((size_t)(j >> 3) * 64 + p) * 8 + (j & 7);
    float vf = b2f(hf[o]);
    float vb = b2f(hb[o]);
    s0 += Pw[j] * vf + Pw[768 + j] * vb;
    s1 += Pw[1536 + j] * vf + Pw[2304 + j] * vb;
  }
  for (int off = 32; off; off >>= 1) {
    s0 += __shfl_down(s0, off, 64);
    s1 += __shfl_down(s1, off, 64);
  }
  if (lane == 0) {
    em[((size_t)(m * 64 + p) * 128 + t) * 2 + 0] = s0 + Pb[0];
    em[((size_t)(m * 64 + p) * 128 + t) * 2 + 1] = s1 + Pb[1];
  }
}

__global__ void final_k(const float* em, const int* labs, const float* T, float* out) {
  int p = threadIdx.x;   // 64 threads, 1 wave
  const float* emP = em + (size_t)p * 128 * 2;
  int lp = 2 * p + 2;
  float T00 = T[0], T01 = T[1], T10 = T[2], T11 = T[3];
  int prevlab = labs[0];
  float gold = emP[prevlab];
  for (int t = 1; t < lp; ++t) {
    int lb = labs[t];
    gold += emP[t * 2 + lb] + (prevlab ? (lb ? T11 : T10) : (lb ? T01 : T00));
    prevlab = lb;
  }
  float a0 = emP[0], a1 = emP[1];
  for (int t = 1; t < lp; ++t) {
    float n0 = lse2(a0 + T00, a1 + T10) + emP[t * 2];
    float n1 = lse2(a0 + T01, a1 + T11) + emP[t * 2 + 1];
    a0 = n0;
    a1 = n1;
  }
  float crf = lse2(a0, a1) - gold;
  const float* emR = em + (size_t)(64 + p) * 128 * 2;
  int lpr = 2 * p + 1;
  float d0 = emR[(lpr - 1) * 2 + 0] - emP[(lp - 1) * 2 + 0];
  float d1 = emR[(lpr - 1) * 2 + 1] - emP[(lp - 1) * 2 + 1];
  float mse = d0 * d0 + d1 * d1;
  for (int off = 32; off; off >>= 1) {
    crf += __shfl_down(crf, off, 64);
    mse += __shfl_down(mse, off, 64);
  }
  if (p == 0) {
    float lc = crf / 64.f;
    float lm = mse / 128.f;
    out[0] = lc;
    out[1] = lm;
    out[2] = lc + 0.1f * lm;
  }
}

// ---------------------------------------------------------------------------
extern "C" void kernel_launch(void* const* d_in, const int* in_sizes, int n_in,
                              void* d_out, int out_size, void* d_ws, size_t ws_size,
                              hipStream_t stream) {
  (void)in_sizes; (void)n_in; (void)out_size;
  if (ws_size < WS_NEED) return;   // diagnosable: output stays poisoned

  const float* user     = (const float*)d_in[0];
  const float* sysr     = (const float*)d_in[1];
  const float* postWih0 = (const float*)d_in[2];
  const float* postWhh0 = (const float*)d_in[3];
  const float* postb0   = (const float*)d_in[4];
  const float* postWih1 = (const float*)d_in[5];
  const float* postWhh1 = (const float*)d_in[6];
  const float* postb1   = (const float*)d_in[7];
  const float* priWih0  = (const float*)d_in[8];
  const float* priWhh0  = (const float*)d_in[9];
  const float* prib0    = (const float*)d_in[10];
  const float* priWih1  = (const float*)d_in[11];
  const float* priWhh1  = (const float*)d_in[12];
  const float* prib1    = (const float*)d_in[13];
  const float* postPW   = (const float*)d_in[14];
  const float* postPb   = (const float*)d_in[15];
  const float* priPW    = (const float*)d_in[16];
  const float* priPb    = (const float*)d_in[17];
  const float* trans    = (const float*)d_in[18];
  const int*   ulab     = (const int*)d_in[19];
  const int*   slab     = (const int*)d_in[20];
  float* out = (float*)d_out;

  char* wsb = (char*)d_ws;
  float* em    = (float*)(wsb + OFF_EM);
  float* xw0   = (float*)(wsb + OFF_XW0);
  float* xw1s  = (float*)(wsb + OFF_XW1);
  u16* seqkp   = (u16*)(wsb + OFF_SEQ);
  int* labs    = (int*)(wsb + OFF_LABS);
  unsigned* bars = (unsigned*)(wsb + OFF_BAR);
  u16* W0kp    = (u16*)(wsb + OFF_W0);
  u16* W1xkp   = (u16*)(wsb + OFF_W1X);
  u16* W1rkp   = (u16*)(wsb + OFF_W1R);
  u16* F0      = (u16*)(wsb + OFF_F0);
  u16* h0f     = (u16*)(wsb + OFF_H0F);
  u16* B0      = (u16*)(wsb + OFF_B0);
  u16* F1      = (u16*)(wsb + OFF_F1);
  u16* B1      = (u16*)(wsb + OFF_B1);

  static bool attr_done = false;
  if (!attr_done) {
    (void)hipFuncSetAttribute(reinterpret_cast<const void*>(phase1_k),
                              hipFuncAttributeMaxDynamicSharedMemorySize, 98304);
    (void)hipFuncSetAttribute(reinterpret_cast<const void*>(phase2_k),
                              hipFuncAttributeMaxDynamicSharedMemorySize, 147456);
    attr_done = true;
  }

  init_zero<<<192, 256, 0, stream>>>(
      F0, F0 + (size_t)129 * SLOT16,
      B0 + (size_t)128 * SLOT64, B0 + (size_t)(129 + 128) * SLOT64,
      F1, F1 + (size_t)129 * SLOT64,
      B1 + (size_t)128 * SLOT64, B1 + (size_t)(129 + 128) * SLOT64, bars);

  build_seq<<<384, 256, 0, stream>>>(user, sysr, ulab, slab, seqkp, labs);

  cvt_w<<<dim3(1152, 12), 256, 0, stream>>>(postWhh0, priWhh0, postWih1, priWih1,
                                            postWhh1, priWhh1, W0kp, W1xkp, W1rkp);

  xw_gemm<<<dim3(48, 4), 256, 0, stream>>>(seqkp, 0ULL, postWih0, priWih0, 768,
                                           postb0, prib0, xw0);

  phase1_k<<<192, 256, 98304, stream>>>(W0kp, xw0, B0, F0, h0f, bars);

  xw_gemm<<<dim3(48, 4), 256, 0, stream>>>(h0f, (unsigned long long)SLOT128,
                                           postWih1, priWih1, 1536, postb1, prib1, xw1s);

  phase2_k<<<192, 256, 147456, stream>>>(W1xkp, W1rkp, xw1s, B0, F1, B1, bars);

  em_k<<<4096, 256, 0, stream>>>(F1, B1, postPW, postPb, priPW, priPb, em);

  final_k<<<1, 64, 0, stream>>>(em, labs, trans, out);
}